// Round 1
// 2246.819 us; speedup vs baseline: 1.1315x; 1.1315x over previous
//
#include <hip/hip_runtime.h>

// 5-layer stacked LSTM, T=512 B=256 IN=64 H=128. Storage fp32; internal bf16
// MFMA with fp32 accum (R3 verified, absmax 4.9e-4).
//
// R6: de-serialize the L3 round trips that dominated R5's 4.8us/step:
//  - per-step __syncthreads() (vmcnt(0) drain of sc1 ring stores) -> raw
//    "s_waitcnt lgkmcnt(0); s_barrier" (LDS h-recurrence ordering only);
//    ring stores drain in the background.
//  - flag publish chunked to every 8 steps (vmcnt(0)+barrier+tid0 store,
//    amortized 1/8). Final publish after the loop (T_STEPS).
//  - consumer watermark: re-poll upstream flag only when prefetch t+2 would
//    outrun it (~1/8 steps). Unconditional asm memory clobber after the
//    conditional spin so prefetch loads can't be statically hoisted above it.
//  - depth-2 register prefetch of ring/x loads (ping-pong named buffers, no
//    runtime indexing). All data waits remain compiler-inserted counted
//    vmcnt; manual waits are only vmcnt(0) drains (count-safe).
// Ring depth 64 >> chunk 8, so chunked flags only add skew, not stalls.
// Fallback: R3 layer-sequential path if ws too small.

typedef unsigned short ushort_t;
typedef unsigned int uint_t;
typedef __attribute__((ext_vector_type(8))) short short8;
typedef __attribute__((ext_vector_type(4))) float floatx4;

#define T_STEPS 512
#define BATCH   256
#define HID     128
#define NL      5
#define NBG     16
#define RING_R  64
#define CHUNK   8
#define FLAG_STRIDE 16
#define SLOT_U  (BATCH * HID / 2)                  // uints per ring slot
#define RING_U  ((size_t)RING_R * SLOT_U)          // uints per layer ring
#define WS_NEED (8192 + 4 * RING_U * 4)

__device__ __forceinline__ ushort_t f2bf(float f) {
  unsigned int u = __float_as_uint(f);
  u += 0x7FFF + ((u >> 16) & 1);  // RNE; values here are finite
  return (ushort_t)(u >> 16);
}
__device__ __forceinline__ float sigm(float x) {
  float e = __builtin_amdgcn_exp2f(-1.442695041f * x);
  return __builtin_amdgcn_rcpf(1.0f + e);
}
__device__ __forceinline__ float tanh_(float x) {
  float e = __builtin_amdgcn_exp2f(-2.885390082f * x);
  float s = __builtin_amdgcn_rcpf(1.0f + e);
  return __builtin_fmaf(2.0f, s, -1.0f);
}
__device__ __forceinline__ int flag_ld(const int* p) {
  return __hip_atomic_load(p, __ATOMIC_RELAXED, __HIP_MEMORY_SCOPE_AGENT);
}
__device__ __forceinline__ uint_t ring_ld(const uint_t* p) {
  return __hip_atomic_load(p, __ATOMIC_RELAXED, __HIP_MEMORY_SCOPE_AGENT);
}
__device__ __forceinline__ void ring_st(uint_t* p, uint_t v) {
  __hip_atomic_store(p, v, __ATOMIC_RELAXED, __HIP_MEMORY_SCOPE_AGENT);
}

__global__ void init_flags(int* flags) {
  int i = blockIdx.x * 256 + threadIdx.x;
  if (i < NL * NBG * FLAG_STRIDE)
    __hip_atomic_store(&flags[i], 0, __ATOMIC_RELAXED,
                       __HIP_MEMORY_SCOPE_AGENT);
}

// ---------------------------------------------------------------- pipeline --
template <int KIN, bool SRC_F32>
__device__ __forceinline__ void lstm_stage(
    const float* xf32,              // layer-0 input (fp32) if SRC_F32
    const uint_t* ring_in,          // upstream ring (packed bf16 pairs)
    const float* __restrict__ Wih, const float* __restrict__ Whh,
    const float* __restrict__ bih, const float* __restrict__ bhh,
    uint_t* ring_out,               // this layer's ring (null for last)
    float* out_f32,                 // d_out (last layer only)
    int* up_flag, int* down_flag, int* my_flag, int bg)
{
  constexpr int KX = KIN / 32;
  const int tid  = threadIdx.x;
  const int wave = tid >> 6;
  const int lane = tid & 63;
  const int col  = lane & 15;        // MFMA: A row / D col
  const int quad = lane >> 4;        // MFMA: k-group / D row-group
  const int j    = wave * 16 + col;  // gate/h column owned by this lane

  __shared__ ushort_t Ah[2][16][136];  // own-h recurrence, double buffered
  for (int i = tid; i < 2 * 16 * 136; i += 512) (&Ah[0][0][0])[i] = 0;

  // Wcat^T fragments, fp32 -> bf16 once, VGPR-resident all 512 steps.
  short8 wf[4][KX + 4];
#pragma unroll
  for (int nt = 0; nt < 4; ++nt) {
    int n = nt * 128 + j;
#pragma unroll
    for (int kt = 0; kt < KX; ++kt) {
      const float* p = Wih + n * KIN + kt * 32 + quad * 8;
      short8 w;
#pragma unroll
      for (int e = 0; e < 8; ++e) w[e] = (short)f2bf(p[e]);
      wf[nt][kt] = w;
    }
#pragma unroll
    for (int kt = 0; kt < 4; ++kt) {
      const float* p = Whh + n * 128 + kt * 32 + quad * 8;
      short8 w;
#pragma unroll
      for (int e = 0; e < 8; ++e) w[e] = (short)f2bf(p[e]);
      wf[nt][KX + kt] = w;
    }
  }
  const float bi  = bih[j]       + bhh[j];
  const float bf_ = bih[128 + j] + bhh[128 + j];
  const float bgi = bih[256 + j] + bhh[256 + j];
  const float bo  = bih[384 + j] + bhh[384 + j];

  floatx4 c = {0.f, 0.f, 0.f, 0.f};
  int down_seen = 0;
  int avail = 0;  // consumer watermark of upstream flag

  // depth-2 prefetch ping-pong buffers (named -> static register indexing)
  floatx4 xA[4], xB[4];        // SRC_F32 path: 16 fp32 per step
  uint_t  uA[4][4], uB[4][4];  // ring path: 16 packed uints per step

  auto x_load = [&](int u, floatx4 (&d)[4]) {
    const float* p = xf32 + ((size_t)u * BATCH + bg * 16 + col) * 64 + quad * 8;
    d[0] = *(const floatx4*)(p);
    d[1] = *(const floatx4*)(p + 4);
    d[2] = *(const floatx4*)(p + 32);
    d[3] = *(const floatx4*)(p + 36);
  };
  auto r_load = [&](int u, uint_t (&d)[4][4]) {
    const uint_t* p = ring_in + (size_t)(u & (RING_R - 1)) * SLOT_U +
                      (bg * 16 + col) * 64 + quad * 4;
#pragma unroll
    for (int kt = 0; kt < 4; ++kt)
#pragma unroll
      for (int e = 0; e < 4; ++e) d[kt][e] = ring_ld(p + kt * 16 + e);
  };

  __syncthreads();  // Ah zero-init visible before first recurrence read

  // prologue: need steps 0 and 1 flagged, then issue both prefetches
  if constexpr (!SRC_F32) {
    while ((avail = flag_ld(up_flag)) < 2) __builtin_amdgcn_s_sleep(1);
  }
  asm volatile("" ::: "memory");
  if constexpr (SRC_F32) { x_load(0, xA); x_load(1, xB); }
  else                   { r_load(0, uA); r_load(1, uB); }

  auto body = [&](int t, floatx4 (&xc)[4], uint_t (&uc)[4][4]) {
    // ---- chunked publish: steps < t are stored & drained ----
    if ((t & (CHUNK - 1)) == 0 && t) {
      asm volatile("s_waitcnt vmcnt(0)\n\ts_barrier" ::: "memory");
      if (tid == 0)
        __hip_atomic_store(my_flag, t, __ATOMIC_RELAXED,
                           __HIP_MEMORY_SCOPE_AGENT);
    }
    // ---- watermark: prefetch of step t+2 must be flagged ----
    if constexpr (!SRC_F32) {
      if (t + 2 < T_STEPS && avail < t + 3) {
        while ((avail = flag_ld(up_flag)) < t + 3) __builtin_amdgcn_s_sleep(1);
      }
    }
    asm volatile("" ::: "memory");  // no load hoisting above the spin
    // ring-reuse guard: slot t%R free once downstream finished step t-R
    if (ring_out) {
      while (t - down_seen >= RING_R) {
        down_seen = flag_ld(down_flag);
        if (t - down_seen >= RING_R) __builtin_amdgcn_s_sleep(1);
      }
      asm volatile("" ::: "memory");
    }

    floatx4 a0 = {0, 0, 0, 0}, a1 = {0, 0, 0, 0}, a2 = {0, 0, 0, 0},
            a3 = {0, 0, 0, 0};
    // h-recurrence MFMAs (LDS-fed)
#pragma unroll
    for (int kt = 0; kt < 4; ++kt) {
      short8 a = *(const short8*)(&Ah[t & 1][col][kt * 32 + quad * 8]);
      a0 = __builtin_amdgcn_mfma_f32_16x16x32_bf16(a, wf[0][KX + kt], a0, 0, 0, 0);
      a1 = __builtin_amdgcn_mfma_f32_16x16x32_bf16(a, wf[1][KX + kt], a1, 0, 0, 0);
      a2 = __builtin_amdgcn_mfma_f32_16x16x32_bf16(a, wf[2][KX + kt], a2, 0, 0, 0);
      a3 = __builtin_amdgcn_mfma_f32_16x16x32_bf16(a, wf[3][KX + kt], a3, 0, 0, 0);
    }
    // x MFMAs (prefetched 2 steps ago; compiler-counted vmcnt wait)
#pragma unroll
    for (int kt = 0; kt < KX; ++kt) {
      short8 a;
      if constexpr (SRC_F32) {
#pragma unroll
        for (int e = 0; e < 4; ++e) {
          a[e]     = (short)f2bf(xc[2 * kt][e]);
          a[4 + e] = (short)f2bf(xc[2 * kt + 1][e]);
        }
      } else {
#pragma unroll
        for (int e = 0; e < 4; ++e) {
          a[2 * e]     = (short)(uc[kt][e] & 0xffff);
          a[2 * e + 1] = (short)(uc[kt][e] >> 16);
        }
      }
      a0 = __builtin_amdgcn_mfma_f32_16x16x32_bf16(a, wf[0][kt], a0, 0, 0, 0);
      a1 = __builtin_amdgcn_mfma_f32_16x16x32_bf16(a, wf[1][kt], a1, 0, 0, 0);
      a2 = __builtin_amdgcn_mfma_f32_16x16x32_bf16(a, wf[2][kt], a2, 0, 0, 0);
      a3 = __builtin_amdgcn_mfma_f32_16x16x32_bf16(a, wf[3][kt], a3, 0, 0, 0);
    }

    // ---- issue prefetch for step t+2 into the buffer just consumed ----
    if (t + 2 < T_STEPS) {
      if constexpr (SRC_F32) x_load(t + 2, xc);
      else                   r_load(t + 2, uc);
    }

    // ---- cell update (lane-local) ----
    ushort_t (*wr)[136] = Ah[(t & 1) ^ 1];
    ushort_t hb[4];
    float hv[4];
#pragma unroll
    for (int r = 0; r < 4; ++r) {
      float iv = sigm(a0[r] + bi);
      float fv = sigm(a1[r] + bf_);
      float gv = tanh_(a2[r] + bgi);
      float ov = sigm(a3[r] + bo);
      float cn = __builtin_fmaf(fv, c[r], iv * gv);
      c[r] = cn;
      hv[r] = ov * tanh_(cn);
      hb[r] = f2bf(hv[r]);
      wr[quad * 4 + r][j] = hb[r];  // own recurrence
    }

    if (ring_out) {
      // pack h-col pairs (j&~1, j|1) via lane^1 exchange -> 2 uint stores/lane
      uint_t other[4];
#pragma unroll
      for (int r = 0; r < 4; ++r)
        other[r] = (uint_t)__shfl_xor((int)hb[r], 1, 64) & 0xffff;
      uint_t* base = ring_out + (size_t)(t & (RING_R - 1)) * SLOT_U +
                     (bg * 16 + quad * 4) * 64 + (j >> 1);
      if ((j & 1) == 0) {
        ring_st(base + 0 * 64, (uint_t)hb[0] | (other[0] << 16));
        ring_st(base + 1 * 64, (uint_t)hb[1] | (other[1] << 16));
      } else {
        ring_st(base + 2 * 64, other[2] | ((uint_t)hb[2] << 16));
        ring_st(base + 3 * 64, other[3] | ((uint_t)hb[3] << 16));
      }
    } else {
      float* ob = out_f32 + ((size_t)t * BATCH + bg * 16 + quad * 4) * HID + j;
#pragma unroll
      for (int r = 0; r < 4; ++r) ob[(size_t)r * HID] = hv[r];
    }

    // LDS-only barrier: orders h double-buffer; ring stores stay in flight
    asm volatile("s_waitcnt lgkmcnt(0)\n\ts_barrier" ::: "memory");
  };

  for (int t = 0; t < T_STEPS; t += 2) {
    body(t,     xA, uA);
    body(t + 1, xB, uB);
  }
  // final publish: all 512 steps stored & drained
  asm volatile("s_waitcnt vmcnt(0)\n\ts_barrier" ::: "memory");
  if (tid == 0)
    __hip_atomic_store(my_flag, T_STEPS, __ATOMIC_RELAXED,
                       __HIP_MEMORY_SCOPE_AGENT);
}

__global__ __launch_bounds__(512) void lstm_pipe(
    const float* x, const float* Wih0, const float* WihR,
    const float* Whh, const float* bih, const float* bhh,
    float* out, uint_t* ring, int* flags)
{
  const int l  = blockIdx.x >> 4;   // blockIdx = l*16+bg -> bg%8 XCD affinity
  const int bg = blockIdx.x & 15;
  int* mine = flags + (l * NBG + bg) * FLAG_STRIDE;
  int* up   = (l > 0) ? flags + ((l - 1) * NBG + bg) * FLAG_STRIDE : nullptr;
  int* down = (l < 4) ? flags + ((l + 1) * NBG + bg) * FLAG_STRIDE : nullptr;

  if (l == 0) {
    lstm_stage<64, true>(x, nullptr, Wih0, Whh, bih, bhh,
                         ring, nullptr, up, down, mine, bg);
  } else if (l < 4) {
    lstm_stage<128, false>(nullptr, ring + (size_t)(l - 1) * RING_U,
                           WihR + (size_t)(l - 1) * 512 * 128,
                           Whh + (size_t)l * 512 * 128,
                           bih + l * 512, bhh + l * 512,
                           ring + (size_t)l * RING_U, nullptr,
                           up, down, mine, bg);
  } else {
    lstm_stage<128, false>(nullptr, ring + (size_t)3 * RING_U,
                           WihR + (size_t)3 * 512 * 128,
                           Whh + (size_t)4 * 512 * 128,
                           bih + 4 * 512, bhh + 4 * 512,
                           nullptr, out, up, nullptr, mine, bg);
  }
}

// ------------------------------------------------- fallback (R3, verified) --
template <int KIN>
__global__ __launch_bounds__(512) void lstm_layer(
    const float* xin, float* hout,
    const float* __restrict__ Wih, const float* __restrict__ Whh,
    const float* __restrict__ bih, const float* __restrict__ bhh)
{
  constexpr int KX = KIN / 32, KT = KX + 4;
  constexpr int AW = KIN + 128, AS = AW + 8;
  constexpr int NSTG = 16 * KIN / 4;

  const int bg = blockIdx.x, tid = threadIdx.x;
  const int wave = tid >> 6, lane = tid & 63;
  const int col = lane & 15, quad = lane >> 4;
  const int j = wave * 16 + col;

  __shared__ __align__(16) ushort_t Ah[2][16][AS];
  for (int i = tid; i < 2 * 16 * AS; i += 512) (&Ah[0][0][0])[i] = 0;

  short8 wf[4][KT];
#pragma unroll
  for (int nt = 0; nt < 4; ++nt) {
    int n = nt * 128 + j;
#pragma unroll
    for (int kt = 0; kt < KX; ++kt) {
      const float* p = Wih + n * KIN + kt * 32 + quad * 8;
      short8 w;
#pragma unroll
      for (int e = 0; e < 8; ++e) w[e] = (short)f2bf(p[e]);
      wf[nt][kt] = w;
    }
#pragma unroll
    for (int kt = 0; kt < 4; ++kt) {
      const float* p = Whh + n * 128 + kt * 32 + quad * 8;
      short8 w;
#pragma unroll
      for (int e = 0; e < 8; ++e) w[e] = (short)f2bf(p[e]);
      wf[nt][KX + kt] = w;
    }
  }
  const float bi  = bih[j]       + bhh[j];
  const float bf_ = bih[128 + j] + bhh[128 + j];
  const float bgi = bih[256 + j] + bhh[256 + j];
  const float bo  = bih[384 + j] + bhh[384 + j];

  floatx4 c = {0.f, 0.f, 0.f, 0.f};
  const int srow = tid / (KIN / 4), scol = (tid % (KIN / 4)) * 4;
  floatx4 xv = {0.f, 0.f, 0.f, 0.f};
  auto stage_load = [&](int t) {
    if (tid < NSTG && t < T_STEPS)
      xv = *(const floatx4*)(xin + (size_t)(t * BATCH + bg * 16 + srow) * KIN + scol);
  };
  auto stage_store = [&](int t, ushort_t (*buf)[AS]) {
    if (tid < NSTG && t < T_STEPS) {
#pragma unroll
      for (int e = 0; e < 4; ++e) buf[srow][scol + e] = f2bf(xv[e]);
    }
  };
  __syncthreads();
  stage_load(0); stage_store(0, Ah[0]); stage_load(1);
  __syncthreads();

  for (int t = 0; t < T_STEPS; ++t) {
    ushort_t (*rd)[AS] = Ah[t & 1];
    ushort_t (*wr)[AS] = Ah[(t & 1) ^ 1];
    short8 af[KT];
#pragma unroll
    for (int kt = 0; kt < KT; ++kt)
      af[kt] = *(const short8*)(&rd[col][kt * 32 + quad * 8]);
    floatx4 a0 = {0, 0, 0, 0}, a1 = {0, 0, 0, 0}, a2 = {0, 0, 0, 0},
            a3 = {0, 0, 0, 0};
#pragma unroll
    for (int kt = 0; kt < KT; ++kt) {
      short8 a = af[kt];
      a0 = __builtin_amdgcn_mfma_f32_16x16x32_bf16(a, wf[0][kt], a0, 0, 0, 0);
      a1 = __builtin_amdgcn_mfma_f32_16x16x32_bf16(a, wf[1][kt], a1, 0, 0, 0);
      a2 = __builtin_amdgcn_mfma_f32_16x16x32_bf16(a, wf[2][kt], a2, 0, 0, 0);
      a3 = __builtin_amdgcn_mfma_f32_16x16x32_bf16(a, wf[3][kt], a3, 0, 0, 0);
    }
    stage_store(t + 1, wr);
    stage_load(t + 2);
    size_t obase = (size_t)(t * BATCH + bg * 16) * HID + j;
#pragma unroll
    for (int r = 0; r < 4; ++r) {
      int row = quad * 4 + r;
      float iv = sigm(a0[r] + bi);
      float fv = sigm(a1[r] + bf_);
      float gv = tanh_(a2[r] + bgi);
      float ov = sigm(a3[r] + bo);
      float cn = __builtin_fmaf(fv, c[r], iv * gv);
      c[r] = cn;
      float hv = ov * tanh_(cn);
      wr[row][KIN + j] = f2bf(hv);
      hout[obase + (size_t)row * HID] = hv;
    }
    __syncthreads();
  }
}

extern "C" void kernel_launch(void* const* d_in, const int* in_sizes, int n_in,
                              void* d_out, int out_size, void* d_ws,
                              size_t ws_size, hipStream_t stream) {
  const float* x    = (const float*)d_in[0];  // [512,256,64]
  const float* Wih0 = (const float*)d_in[1];  // [512,64]
  const float* WihR = (const float*)d_in[2];  // [4,512,128]
  const float* Whh  = (const float*)d_in[3];  // [5,512,128]
  const float* bih  = (const float*)d_in[4];  // [5,512]
  const float* bhh  = (const float*)d_in[5];  // [5,512]
  float* out = (float*)d_out;                 // [512,256,128]

  if (ws_size >= WS_NEED) {
    int* flags = (int*)d_ws;
    uint_t* ring = (uint_t*)((char*)d_ws + 8192);
    init_flags<<<(NL * NBG * FLAG_STRIDE + 255) / 256, 256, 0, stream>>>(flags);
    lstm_pipe<<<NL * NBG, 512, 0, stream>>>(x, Wih0, WihR, Whh, bih, bhh,
                                            out, ring, flags);
  } else {
    lstm_layer<64><<<16, 512, 0, stream>>>(x, out, Wih0, Whh, bih, bhh);
    for (int l = 1; l < 5; ++l)
      lstm_layer<128><<<16, 512, 0, stream>>>(
          out, out, WihR + (size_t)(l - 1) * 512 * 128,
          Whh + (size_t)l * 512 * 128, bih + l * 512, bhh + l * 512);
  }
}

// Round 2
// 945.080 us; speedup vs baseline: 2.6900x; 2.3774x over previous
//
#include <hip/hip_runtime.h>

// 5-layer stacked LSTM, T=512 B=256 IN=64 H=128. Storage fp32; internal bf16
// MFMA with fp32 accum (R3 verified, absmax 4.9e-4).
//
// R7: the R5/R6 period (~10.3k cy/step) was dominated by scattered, redundant
// agent-scope ring traffic: 8 waves x 16 dword loads/step of the SAME 4KB
// tile (L2-bypass, 256B lane stride -> ~2048 L3 line requests per block-step)
// plus 2 scattered stores/lane. R7 makes the handoff cooperative+coalesced:
//  - ring layout [slot][bg][16x128 bf16]: one contiguous 4KB tile per bg.
//  - consumer: ONE 8B agent dwordx2 load per thread -> LDS concat buffer
//    [16][KIN+128]; x and h MFMA fragments both read from LDS (verified R3
//    fallback geometry, 2-way=free banking).
//  - producer: h already in LDS; after barrier, ONE 8B agent store per thread
//    writes the previous step's h tile contiguously (replaces shfl-pack).
//  - layer 0: cooperative coalesced x staging via L1/L2 (fallback pattern).
//  - fence-free relaxed-atomic flags, publish every 8 steps = slots drained.
// Fallback: R3 layer-sequential path if ws too small.

typedef unsigned short ushort_t;
typedef unsigned int uint_t;
typedef unsigned long long ull_t;
typedef __attribute__((ext_vector_type(8))) short short8;
typedef __attribute__((ext_vector_type(4))) float floatx4;

#define T_STEPS 512
#define BATCH   256
#define HID     128
#define NL      5
#define NBG     16
#define RING_R  64
#define CHUNK   8
#define FLAG_STRIDE 16
#define SLOT_U  (BATCH * HID / 2)                  // uints per ring slot
#define RING_U  ((size_t)RING_R * SLOT_U)          // uints per layer ring
#define WS_NEED (8192 + 4 * RING_U * 4)

__device__ __forceinline__ ushort_t f2bf(float f) {
  unsigned int u = __float_as_uint(f);
  u += 0x7FFF + ((u >> 16) & 1);  // RNE; values here are finite
  return (ushort_t)(u >> 16);
}
__device__ __forceinline__ float sigm(float x) {
  float e = __builtin_amdgcn_exp2f(-1.442695041f * x);
  return __builtin_amdgcn_rcpf(1.0f + e);
}
__device__ __forceinline__ float tanh_(float x) {
  float e = __builtin_amdgcn_exp2f(-2.885390082f * x);
  float s = __builtin_amdgcn_rcpf(1.0f + e);
  return __builtin_fmaf(2.0f, s, -1.0f);
}
__device__ __forceinline__ int flag_ld(const int* p) {
  return __hip_atomic_load(p, __ATOMIC_RELAXED, __HIP_MEMORY_SCOPE_AGENT);
}

__global__ void init_flags(int* flags) {
  int i = blockIdx.x * 256 + threadIdx.x;
  if (i < NL * NBG * FLAG_STRIDE)
    __hip_atomic_store(&flags[i], 0, __ATOMIC_RELAXED,
                       __HIP_MEMORY_SCOPE_AGENT);
}

// ---------------------------------------------------------------- pipeline --
// Flag semantics: my_flag = N  <=>  slots 0..N-1 of my ring are stored AND
// drained to the coherence point (L3). Published at body t (t%CHUNK==0): all
// coop stores issued so far cover slots <= t-2, so N = t-1. Consumer reading
// slot s requires up_flag >= s+1. Ring reuse: overwriting slot s requires the
// downstream to have loaded slot s-64; downstream at flag d has loaded slots
// <= d+1, enforced conservatively as  s <= down_seen + (RING_R - 8).
template <int KIN, bool SRC_F32, bool RING_OUT>
__device__ __forceinline__ void lstm_stage(
    const float* xf32,              // layer-0 input (fp32) if SRC_F32
    const uint_t* ring_in,          // upstream ring (bf16 tiles)
    const float* __restrict__ Wih, const float* __restrict__ Whh,
    const float* __restrict__ bih, const float* __restrict__ bhh,
    uint_t* ring_out,               // this layer's ring (RING_OUT)
    float* out_f32,                 // d_out (last layer only)
    int* up_flag, int* down_flag, int* my_flag, int bg)
{
  constexpr int KX = KIN / 32, KT = KX + 4;
  constexpr int AW = KIN + 128, AS = AW + 8;   // concat [x | h] + pad
  constexpr int NSTG = 16 * KIN / 4;           // layer-0 x staging threads

  const int tid  = threadIdx.x;
  const int wave = tid >> 6;
  const int lane = tid & 63;
  const int col  = lane & 15;        // MFMA: A row / D col
  const int quad = lane >> 4;        // MFMA: k-group / D row-group
  const int j    = wave * 16 + col;  // gate/h column owned by this lane

  __shared__ __align__(16) ushort_t Ah[2][16][AS];  // [x | h], double buffered
  for (int i = tid; i < 2 * 16 * AS; i += 512) (&Ah[0][0][0])[i] = 0;

  // Wcat^T fragments, fp32 -> bf16 once, VGPR-resident all 512 steps.
  short8 wf[4][KT];
#pragma unroll
  for (int nt = 0; nt < 4; ++nt) {
    int n = nt * 128 + j;
#pragma unroll
    for (int kt = 0; kt < KX; ++kt) {
      const float* p = Wih + n * KIN + kt * 32 + quad * 8;
      short8 w;
#pragma unroll
      for (int e = 0; e < 8; ++e) w[e] = (short)f2bf(p[e]);
      wf[nt][kt] = w;
    }
#pragma unroll
    for (int kt = 0; kt < 4; ++kt) {
      const float* p = Whh + n * 128 + kt * 32 + quad * 8;
      short8 w;
#pragma unroll
      for (int e = 0; e < 8; ++e) w[e] = (short)f2bf(p[e]);
      wf[nt][KX + kt] = w;
    }
  }
  const float bi  = bih[j]       + bhh[j];
  const float bf_ = bih[128 + j] + bhh[128 + j];
  const float bgi = bih[256 + j] + bhh[256 + j];
  const float bo  = bih[384 + j] + bhh[384 + j];

  floatx4 c = {0.f, 0.f, 0.f, 0.f};
  int down_seen = 0;
  int avail = 0;  // watermark of upstream flag

  // layer-0 x staging (coalesced, cached path) — fallback pattern
  const int srow = tid / (KIN / 4), scol = (tid % (KIN / 4)) * 4;
  floatx4 xv = {0.f, 0.f, 0.f, 0.f};
  auto x_ld = [&](int t) {
    if constexpr (SRC_F32) {
      if (tid < NSTG && t < T_STEPS)
        xv = *(const floatx4*)(xf32 +
                               (size_t)(t * BATCH + bg * 16 + srow) * KIN + scol);
    }
  };
  auto x_st = [&](int t, ushort_t (*buf)[AS]) {
    if constexpr (SRC_F32) {
      if (tid < NSTG && t < T_STEPS) {
#pragma unroll
        for (int e = 0; e < 4; ++e) buf[srow][scol + e] = f2bf(xv[e]);
      }
    }
  };

  // consumer staging: one 8B agent load / thread per step (coalesced tile)
  const int crow = tid >> 5;             // 16 rows
  const int ccol = (tid & 31) * 4;       // 128 cols, 4 ushorts / thread
  ull_t pf = 0;
  auto r_ld = [&](int t) {
    if (t < T_STEPS)
      pf = __hip_atomic_load(
          (const ull_t*)(ring_in + (size_t)(t & (RING_R - 1)) * SLOT_U +
                         bg * 1024) + tid,
          __ATOMIC_RELAXED, __HIP_MEMORY_SCOPE_AGENT);
  };
  auto r_st = [&](int t, ushort_t (*buf)[AS]) {
    if (t < T_STEPS)
      *(ull_t*)(&buf[crow][ccol]) = pf;   // ds_write_b64, 2-way banking (free)
  };

  __syncthreads();  // zero-init visible

  // ---- prologue ----
  if constexpr (SRC_F32) {
    x_ld(0); x_st(0, Ah[0]); x_ld(1);
  } else {
    while ((avail = flag_ld(up_flag)) < 2) __builtin_amdgcn_s_sleep(1);
    asm volatile("" ::: "memory");
    r_ld(0); r_st(0, Ah[0]);  // compiler waits vmcnt before the ds_write
    r_ld(1);                  // pf = slot 1, consumed in body(0)
  }
  __syncthreads();

  for (int t = 0; t < T_STEPS; ++t) {
    // ---- chunked publish: slots <= t-2 stored & drained -> flag = t-1 ----
    if ((t & (CHUNK - 1)) == 0 && t) {
      asm volatile("s_waitcnt vmcnt(0)\n\ts_barrier" ::: "memory");
      if (tid == 0)
        __hip_atomic_store(my_flag, t - 1, __ATOMIC_RELAXED,
                           __HIP_MEMORY_SCOPE_AGENT);
    }
    // ---- watermark: this body prefetches slot t+2 ----
    if constexpr (!SRC_F32) {
      if (t + 2 < T_STEPS && avail < t + 3) {
        while ((avail = flag_ld(up_flag)) < t + 3) __builtin_amdgcn_s_sleep(1);
      }
      asm volatile("" ::: "memory");  // no load hoisting above the spin
    }
    // ---- cooperative ring store of h_{t-1} (contiguous 4KB tile) ----
    if constexpr (RING_OUT) {
      if (t > 0) {
        int s = t - 1;
        while (s - down_seen >= RING_R - 8) {
          down_seen = flag_ld(down_flag);
          if (s - down_seen >= RING_R - 8) __builtin_amdgcn_s_sleep(1);
        }
        asm volatile("" ::: "memory");
        ull_t hv8 = *(const ull_t*)(&Ah[t & 1][crow][KIN + ccol]);
        __hip_atomic_store(
            (ull_t*)(ring_out + (size_t)(s & (RING_R - 1)) * SLOT_U +
                     bg * 1024) + tid,
            hv8, __ATOMIC_RELAXED, __HIP_MEMORY_SCOPE_AGENT);
      }
    }

    ushort_t (*rd)[AS] = Ah[t & 1];
    ushort_t (*wr)[AS] = Ah[(t & 1) ^ 1];

    // ---- stage x_{t+1} into wr; issue prefetch of slot/x t+2 ----
    if constexpr (SRC_F32) { x_st(t + 1, wr); x_ld(t + 2); }
    else                   { r_st(t + 1, wr); r_ld(t + 2); }

    // ---- A fragments + MFMA (verified fallback geometry) ----
    short8 af[KT];
#pragma unroll
    for (int kt = 0; kt < KT; ++kt)
      af[kt] = *(const short8*)(&rd[col][kt * 32 + quad * 8]);
    floatx4 a0 = {0, 0, 0, 0}, a1 = {0, 0, 0, 0}, a2 = {0, 0, 0, 0},
            a3 = {0, 0, 0, 0};
#pragma unroll
    for (int kt = 0; kt < KT; ++kt) {
      short8 a = af[kt];
      a0 = __builtin_amdgcn_mfma_f32_16x16x32_bf16(a, wf[0][kt], a0, 0, 0, 0);
      a1 = __builtin_amdgcn_mfma_f32_16x16x32_bf16(a, wf[1][kt], a1, 0, 0, 0);
      a2 = __builtin_amdgcn_mfma_f32_16x16x32_bf16(a, wf[2][kt], a2, 0, 0, 0);
      a3 = __builtin_amdgcn_mfma_f32_16x16x32_bf16(a, wf[3][kt], a3, 0, 0, 0);
    }

    // ---- cell update (lane-local) ----
#pragma unroll
    for (int r = 0; r < 4; ++r) {
      float iv = sigm(a0[r] + bi);
      float fv = sigm(a1[r] + bf_);
      float gv = tanh_(a2[r] + bgi);
      float ov = sigm(a3[r] + bo);
      float cn = __builtin_fmaf(fv, c[r], iv * gv);
      c[r] = cn;
      float hv = ov * tanh_(cn);
      wr[quad * 4 + r][KIN + j] = f2bf(hv);  // own recurrence + handoff tile
      if constexpr (!RING_OUT) {
        out_f32[((size_t)t * BATCH + bg * 16 + quad * 4 + r) * HID + j] = hv;
      }
    }

    // LDS-only barrier: orders buffers; agent stores stay in flight
    asm volatile("s_waitcnt lgkmcnt(0)\n\ts_barrier" ::: "memory");
  }

  // ---- epilogue: store h_{T-1}, drain, final publish ----
  if constexpr (RING_OUT) {
    int s = T_STEPS - 1;
    while (s - down_seen >= RING_R - 8) {
      down_seen = flag_ld(down_flag);
      if (s - down_seen >= RING_R - 8) __builtin_amdgcn_s_sleep(1);
    }
    asm volatile("" ::: "memory");
    ull_t hv8 = *(const ull_t*)(&Ah[T_STEPS & 1][crow][KIN + ccol]);
    __hip_atomic_store(
        (ull_t*)(ring_out + (size_t)(s & (RING_R - 1)) * SLOT_U + bg * 1024) +
            tid,
        hv8, __ATOMIC_RELAXED, __HIP_MEMORY_SCOPE_AGENT);
  }
  asm volatile("s_waitcnt vmcnt(0)\n\ts_barrier" ::: "memory");
  if (tid == 0)
    __hip_atomic_store(my_flag, T_STEPS, __ATOMIC_RELAXED,
                       __HIP_MEMORY_SCOPE_AGENT);
}

__global__ __launch_bounds__(512) void lstm_pipe(
    const float* x, const float* Wih0, const float* WihR,
    const float* Whh, const float* bih, const float* bhh,
    float* out, uint_t* ring, int* flags)
{
  const int l  = blockIdx.x >> 4;   // blockIdx = l*16+bg -> bg%8 XCD affinity
  const int bg = blockIdx.x & 15;
  int* mine = flags + (l * NBG + bg) * FLAG_STRIDE;
  int* up   = (l > 0) ? flags + ((l - 1) * NBG + bg) * FLAG_STRIDE : nullptr;
  int* down = (l < 4) ? flags + ((l + 1) * NBG + bg) * FLAG_STRIDE : nullptr;

  if (l == 0) {
    lstm_stage<64, true, true>(x, nullptr, Wih0, Whh, bih, bhh,
                               ring, nullptr, up, down, mine, bg);
  } else if (l < 4) {
    lstm_stage<128, false, true>(nullptr, ring + (size_t)(l - 1) * RING_U,
                                 WihR + (size_t)(l - 1) * 512 * 128,
                                 Whh + (size_t)l * 512 * 128,
                                 bih + l * 512, bhh + l * 512,
                                 ring + (size_t)l * RING_U, nullptr,
                                 up, down, mine, bg);
  } else {
    lstm_stage<128, false, false>(nullptr, ring + (size_t)3 * RING_U,
                                  WihR + (size_t)3 * 512 * 128,
                                  Whh + (size_t)4 * 512 * 128,
                                  bih + 4 * 512, bhh + 4 * 512,
                                  nullptr, out, up, nullptr, mine, bg);
  }
}

// ------------------------------------------------- fallback (R3, verified) --
template <int KIN>
__global__ __launch_bounds__(512) void lstm_layer(
    const float* xin, float* hout,
    const float* __restrict__ Wih, const float* __restrict__ Whh,
    const float* __restrict__ bih, const float* __restrict__ bhh)
{
  constexpr int KX = KIN / 32, KT = KX + 4;
  constexpr int AW = KIN + 128, AS = AW + 8;
  constexpr int NSTG = 16 * KIN / 4;

  const int bg = blockIdx.x, tid = threadIdx.x;
  const int wave = tid >> 6, lane = tid & 63;
  const int col = lane & 15, quad = lane >> 4;
  const int j = wave * 16 + col;

  __shared__ __align__(16) ushort_t Ah[2][16][AS];
  for (int i = tid; i < 2 * 16 * AS; i += 512) (&Ah[0][0][0])[i] = 0;

  short8 wf[4][KT];
#pragma unroll
  for (int nt = 0; nt < 4; ++nt) {
    int n = nt * 128 + j;
#pragma unroll
    for (int kt = 0; kt < KX; ++kt) {
      const float* p = Wih + n * KIN + kt * 32 + quad * 8;
      short8 w;
#pragma unroll
      for (int e = 0; e < 8; ++e) w[e] = (short)f2bf(p[e]);
      wf[nt][kt] = w;
    }
#pragma unroll
    for (int kt = 0; kt < 4; ++kt) {
      const float* p = Whh + n * 128 + kt * 32 + quad * 8;
      short8 w;
#pragma unroll
      for (int e = 0; e < 8; ++e) w[e] = (short)f2bf(p[e]);
      wf[nt][KX + kt] = w;
    }
  }
  const float bi  = bih[j]       + bhh[j];
  const float bf_ = bih[128 + j] + bhh[128 + j];
  const float bgi = bih[256 + j] + bhh[256 + j];
  const float bo  = bih[384 + j] + bhh[384 + j];

  floatx4 c = {0.f, 0.f, 0.f, 0.f};
  const int srow = tid / (KIN / 4), scol = (tid % (KIN / 4)) * 4;
  floatx4 xv = {0.f, 0.f, 0.f, 0.f};
  auto stage_load = [&](int t) {
    if (tid < NSTG && t < T_STEPS)
      xv = *(const floatx4*)(xin + (size_t)(t * BATCH + bg * 16 + srow) * KIN + scol);
  };
  auto stage_store = [&](int t, ushort_t (*buf)[AS]) {
    if (tid < NSTG && t < T_STEPS) {
#pragma unroll
      for (int e = 0; e < 4; ++e) buf[srow][scol + e] = f2bf(xv[e]);
    }
  };
  __syncthreads();
  stage_load(0); stage_store(0, Ah[0]); stage_load(1);
  __syncthreads();

  for (int t = 0; t < T_STEPS; ++t) {
    ushort_t (*rd)[AS] = Ah[t & 1];
    ushort_t (*wr)[AS] = Ah[(t & 1) ^ 1];
    short8 af[KT];
#pragma unroll
    for (int kt = 0; kt < KT; ++kt)
      af[kt] = *(const short8*)(&rd[col][kt * 32 + quad * 8]);
    floatx4 a0 = {0, 0, 0, 0}, a1 = {0, 0, 0, 0}, a2 = {0, 0, 0, 0},
            a3 = {0, 0, 0, 0};
#pragma unroll
    for (int kt = 0; kt < KT; ++kt) {
      short8 a = af[kt];
      a0 = __builtin_amdgcn_mfma_f32_16x16x32_bf16(a, wf[0][kt], a0, 0, 0, 0);
      a1 = __builtin_amdgcn_mfma_f32_16x16x32_bf16(a, wf[1][kt], a1, 0, 0, 0);
      a2 = __builtin_amdgcn_mfma_f32_16x16x32_bf16(a, wf[2][kt], a2, 0, 0, 0);
      a3 = __builtin_amdgcn_mfma_f32_16x16x32_bf16(a, wf[3][kt], a3, 0, 0, 0);
    }
    stage_store(t + 1, wr);
    stage_load(t + 2);
    size_t obase = (size_t)(t * BATCH + bg * 16) * HID + j;
#pragma unroll
    for (int r = 0; r < 4; ++r) {
      int row = quad * 4 + r;
      float iv = sigm(a0[r] + bi);
      float fv = sigm(a1[r] + bf_);
      float gv = tanh_(a2[r] + bgi);
      float ov = sigm(a3[r] + bo);
      float cn = __builtin_fmaf(fv, c[r], iv * gv);
      c[r] = cn;
      float hv = ov * tanh_(cn);
      wr[row][KIN + j] = f2bf(hv);
      hout[obase + (size_t)row * HID] = hv;
    }
    __syncthreads();
  }
}

extern "C" void kernel_launch(void* const* d_in, const int* in_sizes, int n_in,
                              void* d_out, int out_size, void* d_ws,
                              size_t ws_size, hipStream_t stream) {
  const float* x    = (const float*)d_in[0];  // [512,256,64]
  const float* Wih0 = (const float*)d_in[1];  // [512,64]
  const float* WihR = (const float*)d_in[2];  // [4,512,128]
  const float* Whh  = (const float*)d_in[3];  // [5,512,128]
  const float* bih  = (const float*)d_in[4];  // [5,512]
  const float* bhh  = (const float*)d_in[5];  // [5,512]
  float* out = (float*)d_out;                 // [512,256,128]

  if (ws_size >= WS_NEED) {
    int* flags = (int*)d_ws;
    uint_t* ring = (uint_t*)((char*)d_ws + 8192);
    init_flags<<<(NL * NBG * FLAG_STRIDE + 255) / 256, 256, 0, stream>>>(flags);
    lstm_pipe<<<NL * NBG, 512, 0, stream>>>(x, Wih0, WihR, Whh, bih, bhh,
                                            out, ring, flags);
  } else {
    lstm_layer<64><<<16, 512, 0, stream>>>(x, out, Wih0, Whh, bih, bhh);
    for (int l = 1; l < 5; ++l)
      lstm_layer<128><<<16, 512, 0, stream>>>(
          out, out, WihR + (size_t)(l - 1) * 512 * 128,
          Whh + (size_t)l * 512 * 128, bih + l * 512, bhh + l * 512);
  }
}

// Round 3
// 888.375 us; speedup vs baseline: 2.8617x; 1.0638x over previous
//
#include <hip/hip_runtime.h>

// 5-layer stacked LSTM, T=512 B=256 IN=64 H=128. Storage fp32; internal bf16
// MFMA with fp32 accum (R3 verified, absmax 4.9e-4).
//
// R8: remove flag-protocol stalls from the steady-state loop (R7 period
// 4150cy vs ~1700cy intrinsic chain):
//  - 8-deep LDS x-ring (fetch window [t+1,t+7], 1 coop fetch/body) gives 7
//    bodies of elasticity vs publish quantization.
//  - LDS flag mirrors: tid0 issues agent flag loads each body, commits them
//    into a 4-slot LDS mirror 2 bodies later; all threads read a broadcast
//    ds_read_b32 (uniform decision, no L3 round trip on critical path).
//  - prologue lag priming: consumer waits up_flag >= 18 before starting, so
//    with CHUNK=4 publishes + 3-body mirror staleness the fetch gate never
//    blocks in steady state. Direct-spin fallbacks kept for liveness only.
//  - publish = {vmcnt(0); s_barrier; tid0 flag store} at t%4==0 (the drain is
//    ~free: each body's staging ds_write already forced the wave's vmcnt).
//  - LDS carved from ONE shared block passed to all template instantiations
//    (separate __shared__ per instantiation SUMS allocations: 46.5KB in R7).
// Fallback: R3 layer-sequential path if ws too small.

typedef unsigned short ushort_t;
typedef unsigned int uint_t;
typedef unsigned long long ull_t;
typedef __attribute__((ext_vector_type(8))) short short8;
typedef __attribute__((ext_vector_type(4))) float floatx4;
typedef __attribute__((ext_vector_type(2))) float floatx2;

#define T_STEPS 512
#define BATCH   256
#define HID     128
#define NL      5
#define NBG     16
#define RING_R  64
#define PRIME   18
#define FLAG_STRIDE 16
#define SLOT_U  (BATCH * HID / 2)                  // uints per ring slot
#define RING_U  ((size_t)RING_R * SLOT_U)          // uints per layer ring
#define WS_NEED (8192 + 4 * RING_U * 4)
#define LDS_BYTES 43552                            // KIN=128 carve (max)

__device__ __forceinline__ ushort_t f2bf(float f) {
  unsigned int u = __float_as_uint(f);
  u += 0x7FFF + ((u >> 16) & 1);  // RNE; values here are finite
  return (ushort_t)(u >> 16);
}
__device__ __forceinline__ float sigm(float x) {
  float e = __builtin_amdgcn_exp2f(-1.442695041f * x);
  return __builtin_amdgcn_rcpf(1.0f + e);
}
__device__ __forceinline__ float tanh_(float x) {
  float e = __builtin_amdgcn_exp2f(-2.885390082f * x);
  float s = __builtin_amdgcn_rcpf(1.0f + e);
  return __builtin_fmaf(2.0f, s, -1.0f);
}
__device__ __forceinline__ int flag_ld(const int* p) {
  return __hip_atomic_load(p, __ATOMIC_RELAXED, __HIP_MEMORY_SCOPE_AGENT);
}
__device__ __forceinline__ ull_t ring_ld8(const uint_t* base, int tid) {
  return __hip_atomic_load((const ull_t*)base + tid, __ATOMIC_RELAXED,
                           __HIP_MEMORY_SCOPE_AGENT);
}
__device__ __forceinline__ void ring_st8(uint_t* base, int tid, ull_t v) {
  __hip_atomic_store((ull_t*)base + tid, v, __ATOMIC_RELAXED,
                     __HIP_MEMORY_SCOPE_AGENT);
}

__global__ void init_flags(int* flags) {
  int i = blockIdx.x * 256 + threadIdx.x;
  if (i < NL * NBG * FLAG_STRIDE)
    __hip_atomic_store(&flags[i], 0, __ATOMIC_RELAXED,
                       __HIP_MEMORY_SCOPE_AGENT);
}

// ---------------------------------------------------------------- pipeline --
// Flag semantics: my_flag = N <=> ring slots 0..N-1 stored AND drained to L3.
// Published at top of body t (t%4==0): exports of bodies <= t-1 (slots <=
// t-2) are drained by the per-wave vmcnt forced at each body's staging write
// + the publish's own vmcnt(0)+s_barrier -> N = t-1. Consumer fetch of slot s
// requires flag >= s+1. Ring reuse: overwrite slot s requires s - down_flag
// <= RING_R-16 (downstream published F at top of its body F+1 -> consumed
// slots <= F; s-64 <= F-16 < F).
template <int KIN, bool SRC_F32, bool RING_OUT>
__device__ __forceinline__ void lstm_stage(
    unsigned char* lds,
    const float* xf32,              // layer-0 input (fp32) if SRC_F32
    const uint_t* ring_in,          // upstream ring (bf16 tiles)
    const float* __restrict__ Wih, const float* __restrict__ Whh,
    const float* __restrict__ bih, const float* __restrict__ bhh,
    uint_t* ring_out,               // this layer's ring (RING_OUT)
    float* out_f32,                 // d_out (last layer only)
    int* up_flag, int* down_flag, int* my_flag, int bg)
{
  constexpr int KX = KIN / 32, KT = KX + 4;
  constexpr int XS = KIN + 8;      // padded x row (ushorts): stride%32w == 4
  constexpr int HS = 128 + 8;

  typedef ushort_t (*XT)[16][XS];
  typedef ushort_t (*HT)[16][HS];
  XT Xr = (XT)lds;                                         // [8][16][XS]
  HT Hr = (HT)(lds + (size_t)8 * 16 * XS * 2);             // [2][16][HS]
  int* upm = (int*)(lds + (size_t)8 * 16 * XS * 2 + (size_t)2 * 16 * HS * 2);
  int* dnm = upm + 4;

  const int tid  = threadIdx.x;
  const int wave = tid >> 6;
  const int lane = tid & 63;
  const int col  = lane & 15;        // MFMA: A row / D col
  const int quad = lane >> 4;        // MFMA: k-group / D row-group
  const int j    = wave * 16 + col;  // gate/h column owned by this lane
  const int frow = tid >> 5;         // staging row (16)
  const int fc   = tid & 31;         // staging col group (32)

  for (int i = tid; i < 2 * 16 * HS; i += 512) (&Hr[0][0][0])[i] = 0;
  if (tid == 0) {
#pragma unroll
    for (int i = 0; i < 4; ++i) { upm[i] = 0; dnm[i] = 0; }  // safe: under-report
  }

  // Wcat^T fragments, fp32 -> bf16 once, VGPR/AGPR-resident all 512 steps.
  short8 wf[4][KT];
#pragma unroll
  for (int nt = 0; nt < 4; ++nt) {
    int n = nt * 128 + j;
#pragma unroll
    for (int kt = 0; kt < KX; ++kt) {
      const float* p = Wih + n * KIN + kt * 32 + quad * 8;
      short8 w;
#pragma unroll
      for (int e = 0; e < 8; ++e) w[e] = (short)f2bf(p[e]);
      wf[nt][kt] = w;
    }
#pragma unroll
    for (int kt = 0; kt < 4; ++kt) {
      const float* p = Whh + n * 128 + kt * 32 + quad * 8;
      short8 w;
#pragma unroll
      for (int e = 0; e < 8; ++e) w[e] = (short)f2bf(p[e]);
      wf[nt][KX + kt] = w;
    }
  }
  const float bi  = bih[j]       + bhh[j];
  const float bf_ = bih[128 + j] + bhh[128 + j];
  const float bgi = bih[256 + j] + bhh[256 + j];
  const float bo  = bih[384 + j] + bhh[384 + j];

  floatx4 c = {0.f, 0.f, 0.f, 0.f};
  int nf;                       // next slot to fetch (uniform)
  int pu = 0, pd = 0;           // tid0 pending flag loads
  ull_t pf = 0;
  floatx2 pxf = {0.f, 0.f};

  __syncthreads();  // zero-init + mirror init visible

  // ---------------- prologue: lag priming + prime 8 slots ----------------
  if constexpr (!SRC_F32) {
    int v = 0;
    while ((v = flag_ld(up_flag)) < PRIME) __builtin_amdgcn_s_sleep(1);
    asm volatile("" ::: "memory");
    if (tid == 0) {
#pragma unroll
      for (int i = 0; i < 4; ++i) upm[i] = v;
      pu = v;
    }
    ull_t pr[8];
#pragma unroll
    for (int s = 0; s < 8; ++s)
      pr[s] = ring_ld8(ring_in + (size_t)s * SLOT_U + bg * 1024, tid);
#pragma unroll
    for (int s = 0; s < 8; ++s)
      *(ull_t*)(&Xr[s][frow][fc * 4]) = pr[s];
  } else {
    floatx2 pr[8];
#pragma unroll
    for (int s = 0; s < 8; ++s)
      pr[s] = *(const floatx2*)(xf32 +
                                ((size_t)s * BATCH + bg * 16 + frow) * 64 +
                                fc * 2);
#pragma unroll
    for (int s = 0; s < 8; ++s)
      *(uint_t*)(&Xr[s][frow][fc * 2]) =
          (uint_t)f2bf(pr[s][0]) | ((uint_t)f2bf(pr[s][1]) << 16);
  }
  nf = 8;
  asm volatile("s_waitcnt lgkmcnt(0)\n\ts_barrier" ::: "memory");

  for (int t = 0; t < T_STEPS; ++t) {
    // ---- publish every 4 bodies (drain ~free; see header comment) ----
    if ((t & 3) == 0 && t >= 4) {
      asm volatile("s_waitcnt vmcnt(0)\n\ts_barrier" ::: "memory");
      if (tid == 0)
        __hip_atomic_store(my_flag, t - 1, __ATOMIC_RELAXED,
                           __HIP_MEMORY_SCOPE_AGENT);
    }
    const int am = upm[t & 3];   // broadcast LDS reads (written body t-2)
    const int dn = dnm[t & 3];

    // ---- starvation fallback (liveness only; never in steady state) ----
    if constexpr (!SRC_F32) {
      if (nf == t) {
        while (flag_ld(up_flag) < t + 1) __builtin_amdgcn_s_sleep(1);
        asm volatile("" ::: "memory");
        ull_t e = ring_ld8(
            ring_in + (size_t)(t & (RING_R - 1)) * SLOT_U + bg * 1024, tid);
        *(ull_t*)(&Xr[t & 7][frow][fc * 4]) = e;
        nf = t + 1;
        asm volatile("s_waitcnt lgkmcnt(0)\n\ts_barrier" ::: "memory");
      }
    }

    // ---- export h_{t-1} (contiguous 4KB tile, fire-and-forget) ----
    if constexpr (RING_OUT) {
      if (t >= 1) {
        const int s = t - 1;
        if (s - dn > RING_R - 16) {                    // rare: direct spin
          while (s - flag_ld(down_flag) > RING_R - 16)
            __builtin_amdgcn_s_sleep(1);
          asm volatile("" ::: "memory");
        }
        ull_t h8 = *(const ull_t*)(&Hr[t & 1][frow][fc * 4]);
        ring_st8(ring_out + (size_t)(s & (RING_R - 1)) * SLOT_U + bg * 1024,
                 tid, h8);
      }
    }

    // ---- fetch issue (early; ds_write commit is late) ----
    bool dofetch;
    if constexpr (SRC_F32) {
      dofetch = (nf <= t + 7) && (nf < T_STEPS);
      if (dofetch)
        pxf = *(const floatx2*)(xf32 +
                                ((size_t)nf * BATCH + bg * 16 + frow) * 64 +
                                fc * 2);
    } else {
      dofetch = (nf <= t + 7) && (nf < T_STEPS) && (am >= nf + 1);
      if (dofetch)
        pf = ring_ld8(
            ring_in + (size_t)(nf & (RING_R - 1)) * SLOT_U + bg * 1024, tid);
    }

    // ---- A fragments + MFMA ----
    short8 af[KT];
#pragma unroll
    for (int kt = 0; kt < KX; ++kt)
      af[kt] = *(const short8*)(&Xr[t & 7][col][kt * 32 + quad * 8]);
#pragma unroll
    for (int kt = 0; kt < 4; ++kt)
      af[KX + kt] = *(const short8*)(&Hr[t & 1][col][kt * 32 + quad * 8]);
    floatx4 a0 = {0, 0, 0, 0}, a1 = {0, 0, 0, 0}, a2 = {0, 0, 0, 0},
            a3 = {0, 0, 0, 0};
#pragma unroll
    for (int kt = 0; kt < KT; ++kt) {
      short8 a = af[kt];
      a0 = __builtin_amdgcn_mfma_f32_16x16x32_bf16(a, wf[0][kt], a0, 0, 0, 0);
      a1 = __builtin_amdgcn_mfma_f32_16x16x32_bf16(a, wf[1][kt], a1, 0, 0, 0);
      a2 = __builtin_amdgcn_mfma_f32_16x16x32_bf16(a, wf[2][kt], a2, 0, 0, 0);
      a3 = __builtin_amdgcn_mfma_f32_16x16x32_bf16(a, wf[3][kt], a3, 0, 0, 0);
    }

    // ---- tid0 flag-mirror maintenance (commit old, issue new) ----
    if (tid == 0) {
      if constexpr (!SRC_F32) {
        upm[(t + 2) & 3] = pu;
        pu = flag_ld(up_flag);
      }
      if constexpr (RING_OUT) {
        dnm[(t + 2) & 3] = pd;
        pd = flag_ld(down_flag);
      }
    }

    // ---- cell update (lane-local) ----
    ushort_t (*wr)[HS] = Hr[(t & 1) ^ 1];
#pragma unroll
    for (int r = 0; r < 4; ++r) {
      float iv = sigm(a0[r] + bi);
      float fv = sigm(a1[r] + bf_);
      float gv = tanh_(a2[r] + bgi);
      float ov = sigm(a3[r] + bo);
      float cn = __builtin_fmaf(fv, c[r], iv * gv);
      c[r] = cn;
      float hv = ov * tanh_(cn);
      wr[quad * 4 + r][j] = f2bf(hv);  // own recurrence (+ export next body)
      if constexpr (!RING_OUT) {
        out_f32[((size_t)t * BATCH + bg * 16 + quad * 4 + r) * HID + j] = hv;
      }
    }

    // ---- fetch commit (vmcnt wait hidden under MFMA+gates) ----
    if (dofetch) {
      if constexpr (SRC_F32)
        *(uint_t*)(&Xr[nf & 7][frow][fc * 2]) =
            (uint_t)f2bf(pxf[0]) | ((uint_t)f2bf(pxf[1]) << 16);
      else
        *(ull_t*)(&Xr[nf & 7][frow][fc * 4]) = pf;
      ++nf;
    }

    // LDS-only barrier: orders buffers; agent stores stay in flight
    asm volatile("s_waitcnt lgkmcnt(0)\n\ts_barrier" ::: "memory");
  }

  // ---- epilogue: export h_{T-1}, drain, final publish ----
  if constexpr (RING_OUT) {
    const int s = T_STEPS - 1;
    while (s - flag_ld(down_flag) > RING_R - 16) __builtin_amdgcn_s_sleep(1);
    asm volatile("" ::: "memory");
    ull_t h8 = *(const ull_t*)(&Hr[T_STEPS & 1][frow][fc * 4]);
    ring_st8(ring_out + (size_t)(s & (RING_R - 1)) * SLOT_U + bg * 1024, tid,
             h8);
  }
  asm volatile("s_waitcnt vmcnt(0)\n\ts_barrier" ::: "memory");
  if (tid == 0)
    __hip_atomic_store(my_flag, T_STEPS, __ATOMIC_RELAXED,
                       __HIP_MEMORY_SCOPE_AGENT);
}

__global__ __launch_bounds__(512) void lstm_pipe(
    const float* x, const float* Wih0, const float* WihR,
    const float* Whh, const float* bih, const float* bhh,
    float* out, uint_t* ring, int* flags)
{
  __shared__ __align__(16) unsigned char lds_raw[LDS_BYTES];
  const int l  = blockIdx.x >> 4;   // blockIdx = l*16+bg -> bg%8 XCD affinity
  const int bg = blockIdx.x & 15;
  int* mine = flags + (l * NBG + bg) * FLAG_STRIDE;
  int* up   = (l > 0) ? flags + ((l - 1) * NBG + bg) * FLAG_STRIDE : nullptr;
  int* down = (l < 4) ? flags + ((l + 1) * NBG + bg) * FLAG_STRIDE : nullptr;

  if (l == 0) {
    lstm_stage<64, true, true>(lds_raw, x, nullptr, Wih0, Whh, bih, bhh,
                               ring, nullptr, up, down, mine, bg);
  } else if (l < 4) {
    lstm_stage<128, false, true>(lds_raw, nullptr,
                                 ring + (size_t)(l - 1) * RING_U,
                                 WihR + (size_t)(l - 1) * 512 * 128,
                                 Whh + (size_t)l * 512 * 128,
                                 bih + l * 512, bhh + l * 512,
                                 ring + (size_t)l * RING_U, nullptr,
                                 up, down, mine, bg);
  } else {
    lstm_stage<128, false, false>(lds_raw, nullptr,
                                  ring + (size_t)3 * RING_U,
                                  WihR + (size_t)3 * 512 * 128,
                                  Whh + (size_t)4 * 512 * 128,
                                  bih + 4 * 512, bhh + 4 * 512,
                                  nullptr, out, up, nullptr, mine, bg);
  }
}

// ------------------------------------------------- fallback (R3, verified) --
template <int KIN>
__global__ __launch_bounds__(512) void lstm_layer(
    const float* xin, float* hout,
    const float* __restrict__ Wih, const float* __restrict__ Whh,
    const float* __restrict__ bih, const float* __restrict__ bhh)
{
  constexpr int KX = KIN / 32, KT = KX + 4;
  constexpr int AW = KIN + 128, AS = AW + 8;
  constexpr int NSTG = 16 * KIN / 4;

  const int bg = blockIdx.x, tid = threadIdx.x;
  const int wave = tid >> 6, lane = tid & 63;
  const int col = lane & 15, quad = lane >> 4;
  const int j = wave * 16 + col;

  __shared__ __align__(16) ushort_t Ah[2][16][AS];
  for (int i = tid; i < 2 * 16 * AS; i += 512) (&Ah[0][0][0])[i] = 0;

  short8 wf[4][KT];
#pragma unroll
  for (int nt = 0; nt < 4; ++nt) {
    int n = nt * 128 + j;
#pragma unroll
    for (int kt = 0; kt < KX; ++kt) {
      const float* p = Wih + n * KIN + kt * 32 + quad * 8;
      short8 w;
#pragma unroll
      for (int e = 0; e < 8; ++e) w[e] = (short)f2bf(p[e]);
      wf[nt][kt] = w;
    }
#pragma unroll
    for (int kt = 0; kt < 4; ++kt) {
      const float* p = Whh + n * 128 + kt * 32 + quad * 8;
      short8 w;
#pragma unroll
      for (int e = 0; e < 8; ++e) w[e] = (short)f2bf(p[e]);
      wf[nt][KX + kt] = w;
    }
  }
  const float bi  = bih[j]       + bhh[j];
  const float bf_ = bih[128 + j] + bhh[128 + j];
  const float bgi = bih[256 + j] + bhh[256 + j];
  const float bo  = bih[384 + j] + bhh[384 + j];

  floatx4 c = {0.f, 0.f, 0.f, 0.f};
  const int srow = tid / (KIN / 4), scol = (tid % (KIN / 4)) * 4;
  floatx4 xv = {0.f, 0.f, 0.f, 0.f};
  auto stage_load = [&](int t) {
    if (tid < NSTG && t < T_STEPS)
      xv = *(const floatx4*)(xin + (size_t)(t * BATCH + bg * 16 + srow) * KIN + scol);
  };
  auto stage_store = [&](int t, ushort_t (*buf)[AS]) {
    if (tid < NSTG && t < T_STEPS) {
#pragma unroll
      for (int e = 0; e < 4; ++e) buf[srow][scol + e] = f2bf(xv[e]);
    }
  };
  __syncthreads();
  stage_load(0); stage_store(0, Ah[0]); stage_load(1);
  __syncthreads();

  for (int t = 0; t < T_STEPS; ++t) {
    ushort_t (*rd)[AS] = Ah[t & 1];
    ushort_t (*wr)[AS] = Ah[(t & 1) ^ 1];
    short8 af[KT];
#pragma unroll
    for (int kt = 0; kt < KT; ++kt)
      af[kt] = *(const short8*)(&rd[col][kt * 32 + quad * 8]);
    floatx4 a0 = {0, 0, 0, 0}, a1 = {0, 0, 0, 0}, a2 = {0, 0, 0, 0},
            a3 = {0, 0, 0, 0};
#pragma unroll
    for (int kt = 0; kt < KT; ++kt) {
      short8 a = af[kt];
      a0 = __builtin_amdgcn_mfma_f32_16x16x32_bf16(a, wf[0][kt], a0, 0, 0, 0);
      a1 = __builtin_amdgcn_mfma_f32_16x16x32_bf16(a, wf[1][kt], a1, 0, 0, 0);
      a2 = __builtin_amdgcn_mfma_f32_16x16x32_bf16(a, wf[2][kt], a2, 0, 0, 0);
      a3 = __builtin_amdgcn_mfma_f32_16x16x32_bf16(a, wf[3][kt], a3, 0, 0, 0);
    }
    stage_store(t + 1, wr);
    stage_load(t + 2);
    size_t obase = (size_t)(t * BATCH + bg * 16) * HID + j;
#pragma unroll
    for (int r = 0; r < 4; ++r) {
      int row = quad * 4 + r;
      float iv = sigm(a0[r] + bi);
      float fv = sigm(a1[r] + bf_);
      float gv = tanh_(a2[r] + bgi);
      float ov = sigm(a3[r] + bo);
      float cn = __builtin_fmaf(fv, c[r], iv * gv);
      c[r] = cn;
      float hv = ov * tanh_(cn);
      wr[row][KIN + j] = f2bf(hv);
      hout[obase + (size_t)row * HID] = hv;
    }
    __syncthreads();
  }
}

extern "C" void kernel_launch(void* const* d_in, const int* in_sizes, int n_in,
                              void* d_out, int out_size, void* d_ws,
                              size_t ws_size, hipStream_t stream) {
  const float* x    = (const float*)d_in[0];  // [512,256,64]
  const float* Wih0 = (const float*)d_in[1];  // [512,64]
  const float* WihR = (const float*)d_in[2];  // [4,512,128]
  const float* Whh  = (const float*)d_in[3];  // [5,512,128]
  const float* bih  = (const float*)d_in[4];  // [5,512]
  const float* bhh  = (const float*)d_in[5];  // [5,512]
  float* out = (float*)d_out;                 // [512,256,128]

  if (ws_size >= WS_NEED) {
    int* flags = (int*)d_ws;
    uint_t* ring = (uint_t*)((char*)d_ws + 8192);
    init_flags<<<(NL * NBG * FLAG_STRIDE + 255) / 256, 256, 0, stream>>>(flags);
    lstm_pipe<<<NL * NBG, 512, 0, stream>>>(x, Wih0, WihR, Whh, bih, bhh,
                                            out, ring, flags);
  } else {
    lstm_layer<64><<<16, 512, 0, stream>>>(x, out, Wih0, Whh, bih, bhh);
    for (int l = 1; l < 5; ++l)
      lstm_layer<128><<<16, 512, 0, stream>>>(
          out, out, WihR + (size_t)(l - 1) * 512 * 128,
          Whh + (size_t)l * 512 * 128, bih + l * 512, bhh + l * 512);
  }
}